// Round 1
// baseline (130.357 us; speedup 1.0000x reference)
//
#include <hip/hip_runtime.h>

// LogSignature depth-4, C=16, B=64, L=256, fp32.
// out per batch: [lvl1(16) | lvl2(256) | lvl3(4096) | lvl4(65536)] = 69904
// ws layout: [dx: B*255*16 f32][sig123: B*4368 f32]  (~2.2 MB)

#define NC 16
#define NL 256
#define NB 64
#define NSTEP 255
#define OUTB 69904
#define SIG123 4368   // 16 + 256 + 4096
#define OFF_L2 16
#define OFF_L3 272
#define OFF_L4 4368

__global__ void k_dx(const float* __restrict__ path, float* __restrict__ dx) {
    int idx = blockIdx.x * blockDim.x + threadIdx.x;
    const int total = NB * NSTEP * NC;
    if (idx >= total) return;
    int i = idx & (NC - 1);
    int t = (idx >> 4) % NSTEP;
    int j = idx / (NC * NSTEP);
    dx[idx] = path[((size_t)j * NL + t + 1) * NC + i] - path[((size_t)j * NL + t) * NC + i];
}

// One block per (batch j, first-index a). Thread (b,c) owns s3[a,b,c] and
// s4[a,b,c,0..15] in registers; s1[a], s2[a,b] maintained redundantly per
// thread (registers). No LDS, no syncs in the scan loop.
__global__ __launch_bounds__(256, 4) void k_scan(const float* __restrict__ dx,
                                                 float* __restrict__ out,
                                                 float* __restrict__ sig123) {
    const int bid = blockIdx.x;
    const int j = bid >> 4;
    const int a = bid & 15;
    const int tid = threadIdx.x;
    const int b = tid >> 4;
    const int c = tid & 15;

    float s4[16];
#pragma unroll
    for (int d = 0; d < 16; ++d) s4[d] = 0.f;
    float s3 = 0.f, s2ab = 0.f, s1a = 0.f;

    const float* dxj = dx + (size_t)j * NSTEP * NC;

    for (int t = 0; t < NSTEP; ++t) {
        const float* r = dxj + t * NC;
        // full dx vector (uniform across the block; L1/L2 broadcast)
        const float4 q0 = *(const float4*)(r);
        const float4 q1 = *(const float4*)(r + 4);
        const float4 q2 = *(const float4*)(r + 8);
        const float4 q3 = *(const float4*)(r + 12);
        // lane-dependent components (dynamic index -> direct loads, same line)
        const float dxa = r[a];
        const float dxb = r[b];
        const float dxc = r[c];

        // T = s3 + dxc*(s2ab/2 + s1a*dxb/6 + dxa*dxb/24)   (old values)
        const float pre4 = fmaf(dxb, fmaf(1.f / 6.f, s1a, (1.f / 24.f) * dxa), 0.5f * s2ab);
        const float T = fmaf(dxc, pre4, s3);

        const float dv[16] = {q0.x, q0.y, q0.z, q0.w, q1.x, q1.y, q1.z, q1.w,
                              q2.x, q2.y, q2.z, q2.w, q3.x, q3.y, q3.z, q3.w};
#pragma unroll
        for (int d = 0; d < 16; ++d) s4[d] = fmaf(dv[d], T, s4[d]);

        // s3 += dxc*(s2ab + s1a*dxb/2 + dxa*dxb/6)         (old s2ab, s1a)
        const float U = fmaf(dxb, fmaf(0.5f, s1a, (1.f / 6.f) * dxa), s2ab);
        s3 = fmaf(dxc, U, s3);
        // s2 += dxb*(s1a + dxa/2)                           (old s1a)
        s2ab = fmaf(dxb, fmaf(0.5f, dxa, s1a), s2ab);
        s1a += dxa;
    }

    float* outj = out + (size_t)j * OUTB;
    float* o4 = outj + OFF_L4 + ((a * 16 + b) * 16 + c) * 16;
#pragma unroll
    for (int d = 0; d < 16; d += 4)
        *(float4*)(o4 + d) = make_float4(s4[d], s4[d + 1], s4[d + 2], s4[d + 3]);

    float* sg = sig123 + (size_t)j * SIG123;
    sg[OFF_L3 + (a * 16 + b) * 16 + c] = s3;
    if (c == 0) sg[OFF_L2 + a * 16 + b] = s2ab;
    if (tid == 0) sg[a] = s1a;
}

// log of signature, in place on out's level-4 region + fills levels 1..3.
// res4[a,b,c,d] = s4 - 1/2(s1a*s3[bcd] + s2ab*s2[cd] + s3abc*s1[d])
//                    + 1/3(s1a*s1b*s2[cd] + s1a*s2bc*s1[d] + s2ab*s1c*s1[d])
//                    - 1/4 s1a*s1b*s1c*s1[d]
__global__ __launch_bounds__(256) void k_log(const float* __restrict__ sig123,
                                             float* __restrict__ out) {
    const int bid = blockIdx.x;
    const int j = bid >> 4;
    const int a = bid & 15;
    const int tid = threadIdx.x;
    const int b = tid >> 4;
    const int c = tid & 15;

    const float* sg = sig123 + (size_t)j * SIG123;
    const float* s1 = sg;
    const float* s2 = sg + OFF_L2;
    const float* s3 = sg + OFF_L3;

    const float s1a = s1[a], s1b = s1[b], s1c = s1[c];
    const float s2ab = s2[a * 16 + b];
    const float s2bc = s2[b * 16 + c];
    const float s3abc = s3[(a * 16 + b) * 16 + c];

    float* outj = out + (size_t)j * OUTB;

    // level-4 per-thread scalar coefficients (group by the d-vector)
    const float A = -0.5f * s1a;
    const float Bv = fmaf((1.f / 3.f) * s1a, s1b, -0.5f * s2ab);
    const float Cv = -0.5f * s3abc + (1.f / 3.f) * fmaf(s1a, s2bc, s2ab * s1c)
                     - 0.25f * s1a * s1b * s1c;

    float* o4 = outj + OFF_L4 + ((a * 16 + b) * 16 + c) * 16;
    const float* s3v = s3 + (b * 16 + c) * 16;  // s3[b,c,:]
    const float* s2v = s2 + c * 16;             // s2[c,:]
#pragma unroll
    for (int d0 = 0; d0 < 16; d0 += 4) {
        float4 v4 = *(const float4*)(o4 + d0);
        float4 v3 = *(const float4*)(s3v + d0);
        float4 v2 = *(const float4*)(s2v + d0);
        float4 v1 = *(const float4*)(s1 + d0);
        float4 rr;
        rr.x = fmaf(A, v3.x, v4.x) + fmaf(Bv, v2.x, Cv * v1.x);
        rr.y = fmaf(A, v3.y, v4.y) + fmaf(Bv, v2.y, Cv * v1.y);
        rr.z = fmaf(A, v3.z, v4.z) + fmaf(Bv, v2.z, Cv * v1.z);
        rr.w = fmaf(A, v3.w, v4.w) + fmaf(Bv, v2.w, Cv * v1.w);
        *(float4*)(o4 + d0) = rr;
    }

    // level 3
    const float r3 = s3abc - 0.5f * fmaf(s1a, s2bc, s2ab * s1c)
                     + (1.f / 3.f) * s1a * s1b * s1c;
    outj[OFF_L3 + (a * 16 + b) * 16 + c] = r3;
    // level 2
    if (c == 0) outj[OFF_L2 + a * 16 + b] = fmaf(-0.5f * s1a, s1b, s2ab);
    // level 1
    if (tid == 0) outj[a] = s1a;
}

extern "C" void kernel_launch(void* const* d_in, const int* in_sizes, int n_in,
                              void* d_out, int out_size, void* d_ws, size_t ws_size,
                              hipStream_t stream) {
    const float* path = (const float*)d_in[0];
    float* out = (float*)d_out;
    float* dx = (float*)d_ws;
    float* sig123 = dx + (size_t)NB * NSTEP * NC;

    const int total_dx = NB * NSTEP * NC;
    k_dx<<<(total_dx + 255) / 256, 256, 0, stream>>>(path, dx);
    k_scan<<<NB * 16, 256, 0, stream>>>(dx, out, sig123);
    k_log<<<NB * 16, 256, 0, stream>>>(sig123, out);
}

// Round 2
// 124.782 us; speedup vs baseline: 1.0447x; 1.0447x over previous
//
#include <hip/hip_runtime.h>

// LogSignature depth-4, C=16, B=64, L=256, fp32.
// out per batch: [lvl1(16) | lvl2(256) | lvl3(4096) | lvl4(65536)] = 69904
// ws layout (floats):
//   dx1 [j][t][i]   : 64*255*16 = 261120   (time-major, for wave-uniform row loads)
//   dxt [j][i][256] : 64*16*256 = 262144   (component-major, for per-lane float4 loads)
//   sig123 [j][4368]: 64*4368   = 279552
// total ~3.2 MB

#define NC 16
#define NL 256
#define NB 64
#define NSTEP 255
#define OUTB 69904
#define SIG123 4368
#define OFF_L2 16
#define OFF_L3 272
#define OFF_L4 4368

#define DX1_OFF 0
#define DXT_OFF 261120
#define SIG_OFF (261120 + 262144)

// One block per batch j: stage path[j] (16 KB) in LDS, emit both dx layouts.
__global__ __launch_bounds__(256) void k_dx(const float* __restrict__ path,
                                            float* __restrict__ dx1,
                                            float* __restrict__ dxt) {
    const int j = blockIdx.x;
    const int tid = threadIdx.x;
    __shared__ float L[NL * NC];  // 16 KB, [t][i]

    const float* pj = path + (size_t)j * NL * NC;
#pragma unroll
    for (int k = 0; k < 4; ++k) {
        const int f = tid + k * 256;  // float4 index
        *(float4*)&L[f * 4] = *(const float4*)&pj[f * 4];
    }
    __syncthreads();

    // time-major diffs (coalesced)
    float* d1 = dx1 + (size_t)j * NSTEP * NC;
    for (int f = tid; f < NSTEP * NC; f += 256) d1[f] = L[f + NC] - L[f];

    // component-major diffs: iter k = row i, lane = t
    float* dt = dxt + (size_t)j * NC * 256;
#pragma unroll
    for (int k = 0; k < NC; ++k) {
        const int t = tid;
        if (t < NSTEP) dt[k * 256 + t] = L[(t + 1) * NC + k] - L[t * NC + k];
    }
}

// One block per (batch j, first-index a). Thread (b,c) owns s3[a,b,c] and
// s4[a,b,c,0..15] in registers; s1[a], s2[a,b] maintained redundantly.
__global__ __launch_bounds__(256, 4) void k_scan(const float* __restrict__ dx1,
                                                 const float* __restrict__ dxt,
                                                 float* __restrict__ out,
                                                 float* __restrict__ sig123) {
    const int bid = blockIdx.x;
    const int j = bid >> 4;
    const int a = bid & 15;
    const int tid = threadIdx.x;
    const int b = tid >> 4;
    const int c = tid & 15;

    float s4[16];
#pragma unroll
    for (int d = 0; d < 16; ++d) s4[d] = 0.f;
    float s3 = 0.f, s2ab = 0.f, s1a = 0.f;

    const float* row0 = dx1 + (size_t)j * NSTEP * NC;       // [t][16], uniform
    const float* ra = dxt + ((size_t)j * NC + a) * 256;      // uniform
    const float* rb = dxt + ((size_t)j * NC + b) * 256;      // per-lane stream
    const float* rc = dxt + ((size_t)j * NC + c) * 256;

    int t = 0;
    for (int it = 0; it < 63; ++it, t += 4) {
        const float4 vb = *(const float4*)(rb + t);  // 4 steps of dxb
        const float4 vc = *(const float4*)(rc + t);
        const float4 va = *(const float4*)(ra + t);  // uniform -> scalar load
#pragma unroll
        for (int u = 0; u < 4; ++u) {
            const float* r = row0 + (t + u) * NC;  // uniform row
            const float4 q0 = *(const float4*)(r);
            const float4 q1 = *(const float4*)(r + 4);
            const float4 q2 = *(const float4*)(r + 8);
            const float4 q3 = *(const float4*)(r + 12);
            const float dxa = (u == 0) ? va.x : (u == 1) ? va.y : (u == 2) ? va.z : va.w;
            const float dxb = (u == 0) ? vb.x : (u == 1) ? vb.y : (u == 2) ? vb.z : vb.w;
            const float dxc = (u == 0) ? vc.x : (u == 1) ? vc.y : (u == 2) ? vc.z : vc.w;

            const float pre4 = fmaf(dxb, fmaf(1.f / 6.f, s1a, (1.f / 24.f) * dxa), 0.5f * s2ab);
            const float T = fmaf(dxc, pre4, s3);
            const float dv[16] = {q0.x, q0.y, q0.z, q0.w, q1.x, q1.y, q1.z, q1.w,
                                  q2.x, q2.y, q2.z, q2.w, q3.x, q3.y, q3.z, q3.w};
#pragma unroll
            for (int d = 0; d < 16; ++d) s4[d] = fmaf(dv[d], T, s4[d]);

            const float U = fmaf(dxb, fmaf(0.5f, s1a, (1.f / 6.f) * dxa), s2ab);
            s3 = fmaf(dxc, U, s3);
            s2ab = fmaf(dxb, fmaf(0.5f, dxa, s1a), s2ab);
            s1a += dxa;
        }
    }
    // tail: t = 252..254
    for (; t < NSTEP; ++t) {
        const float* r = row0 + t * NC;
        const float4 q0 = *(const float4*)(r);
        const float4 q1 = *(const float4*)(r + 4);
        const float4 q2 = *(const float4*)(r + 8);
        const float4 q3 = *(const float4*)(r + 12);
        const float dxa = ra[t];
        const float dxb = rb[t];
        const float dxc = rc[t];
        const float pre4 = fmaf(dxb, fmaf(1.f / 6.f, s1a, (1.f / 24.f) * dxa), 0.5f * s2ab);
        const float T = fmaf(dxc, pre4, s3);
        const float dv[16] = {q0.x, q0.y, q0.z, q0.w, q1.x, q1.y, q1.z, q1.w,
                              q2.x, q2.y, q2.z, q2.w, q3.x, q3.y, q3.z, q3.w};
#pragma unroll
        for (int d = 0; d < 16; ++d) s4[d] = fmaf(dv[d], T, s4[d]);
        const float U = fmaf(dxb, fmaf(0.5f, s1a, (1.f / 6.f) * dxa), s2ab);
        s3 = fmaf(dxc, U, s3);
        s2ab = fmaf(dxb, fmaf(0.5f, dxa, s1a), s2ab);
        s1a += dxa;
    }

    // epilogue: stage s4 slice in LDS, write block's contiguous 16 KB coalesced
    __shared__ float ls[4096];
#pragma unroll
    for (int d = 0; d < 16; d += 4)
        *(float4*)&ls[tid * 16 + d] = make_float4(s4[d], s4[d + 1], s4[d + 2], s4[d + 3]);
    __syncthreads();

    float* o4 = out + (size_t)j * OUTB + OFF_L4 + a * 4096;
#pragma unroll
    for (int k = 0; k < 4; ++k) {
        const int f = tid + k * 256;  // float4 index 0..1023
        *(float4*)(o4 + f * 4) = *(const float4*)&ls[f * 4];
    }

    float* sg = sig123 + (size_t)j * SIG123;
    sg[OFF_L3 + (a * 16 + b) * 16 + c] = s3;
    if (c == 0) sg[OFF_L2 + a * 16 + b] = s2ab;
    if (tid == 0) sg[a] = s1a;
}

// log of signature. Block (j,a); level-4 slice accessed coalesced:
// consecutive lanes -> consecutive float4s.
// res4[a,b,c,d] = s4 - 1/2(s1a*s3[bcd] + s2ab*s2[cd] + s3abc*s1[d])
//                    + 1/3(s1a*s1b*s2[cd] + s1a*s2bc*s1[d] + s2ab*s1c*s1[d])
//                    - 1/4 s1a*s1b*s1c*s1[d]
__global__ __launch_bounds__(256) void k_log(const float* __restrict__ sig123,
                                             float* __restrict__ out) {
    const int bid = blockIdx.x;
    const int j = bid >> 4;
    const int a = bid & 15;
    const int tid = threadIdx.x;

    const float* sg = sig123 + (size_t)j * SIG123;
    const float* s1 = sg;
    const float* s2 = sg + OFF_L2;
    const float* s3 = sg + OFF_L3;

    const float s1a = s1[a];
    float* outj = out + (size_t)j * OUTB;
    float* o4 = outj + OFF_L4 + a * 4096;
    const float A = -0.5f * s1a;

#pragma unroll
    for (int k = 0; k < 4; ++k) {
        const int f = tid + k * 256;   // float4 index within slice, 0..1023
        const int m0 = f * 4;          // element offset: b*256 + c*16 + d0
        const int b = m0 >> 8;
        const int c = (m0 >> 4) & 15;
        const float s1b = s1[b], s1c = s1[c];
        const float s2ab = s2[a * 16 + b];
        const float s2bc = s2[b * 16 + c];
        const float s3abc = s3[m0 >> 4];  // (b*16+c) within slice... careful: s3 index = (a*16+b)*16+c
        const float s3abc_real = s3[(a * 16 + b) * 16 + c];
        (void)s3abc;

        const float Bv = fmaf((1.f / 3.f) * s1a, s1b, -0.5f * s2ab);
        const float Cv = -0.5f * s3abc_real + (1.f / 3.f) * fmaf(s1a, s2bc, s2ab * s1c)
                         - 0.25f * s1a * s1b * s1c;

        const float4 v4 = *(const float4*)(o4 + m0);
        const float4 v3 = *(const float4*)(s3 + m0);          // s3[b,c,d0..]
        const float4 v2 = *(const float4*)(s2 + (m0 & 255));  // s2[c,d0..]
        const float4 v1 = *(const float4*)(s1 + (m0 & 15));   // s1[d0..]
        float4 rr;
        rr.x = fmaf(A, v3.x, v4.x) + fmaf(Bv, v2.x, Cv * v1.x);
        rr.y = fmaf(A, v3.y, v4.y) + fmaf(Bv, v2.y, Cv * v1.y);
        rr.z = fmaf(A, v3.z, v4.z) + fmaf(Bv, v2.z, Cv * v1.z);
        rr.w = fmaf(A, v3.w, v4.w) + fmaf(Bv, v2.w, Cv * v1.w);
        *(float4*)(o4 + m0) = rr;
    }

    // level 3 (coalesced: consecutive tid -> consecutive elements)
    {
        const int b = tid >> 4, c = tid & 15;
        const float s1b = s1[b], s1c = s1[c];
        const float s2ab = s2[a * 16 + b];
        const float s2bc = s2[b * 16 + c];
        const float s3abc = s3[(a * 16 + b) * 16 + c];
        const float r3 = s3abc - 0.5f * fmaf(s1a, s2bc, s2ab * s1c)
                         + (1.f / 3.f) * s1a * s1b * s1c;
        outj[OFF_L3 + a * 256 + tid] = r3;
    }
    // level 2
    if (tid < 16) outj[OFF_L2 + a * 16 + tid] = fmaf(-0.5f * s1a, s1[tid], s2[a * 16 + tid]);
    // level 1
    if (tid == 0) outj[a] = s1a;
}

extern "C" void kernel_launch(void* const* d_in, const int* in_sizes, int n_in,
                              void* d_out, int out_size, void* d_ws, size_t ws_size,
                              hipStream_t stream) {
    const float* path = (const float*)d_in[0];
    float* out = (float*)d_out;
    float* ws = (float*)d_ws;
    float* dx1 = ws + DX1_OFF;
    float* dxt = ws + DXT_OFF;
    float* sig123 = ws + SIG_OFF;

    k_dx<<<NB, 256, 0, stream>>>(path, dx1, dxt);
    k_scan<<<NB * 16, 256, 0, stream>>>(dx1, dxt, out, sig123);
    k_log<<<NB * 16, 256, 0, stream>>>(sig123, out);
}